// Round 5
// baseline (1085.309 us; speedup 1.0000x reference)
//
#include <hip/hip_runtime.h>
#include <math.h>

#define IMG   56
#define WINSZ 7
#define SHIFTSZ 3
#define CDIM  256
#define NH    8
#define DH    32
#define SEQ   49
#define NYW   8
#define NWIN  64
#define NMLP  1024
#define BATCH 32
#define NTOK  (BATCH*IMG*IMG)       // 100352
#define BNW   (BATCH*NWIN)          // 2048
#define SZT   ((size_t)NTOK*CDIM)   // 25,690,112
#define QSCALE 0.17677669529663687f
#define EPSLN 1e-5f

typedef __attribute__((ext_vector_type(8))) short short8;
typedef __attribute__((ext_vector_type(4))) float f32x4;

__device__ __forceinline__ float bf2f(unsigned short u) {
    union { unsigned i; float f; } c; c.i = ((unsigned)u) << 16; return c.f;
}
__device__ __forceinline__ unsigned short f2bf(float f) {
    union { float f; unsigned i; } c; c.f = f;
    unsigned r = c.i + 0x7fffu + ((c.i >> 16) & 1u);   // RNE (finite inputs)
    return (unsigned short)(r >> 16);
}

// fast erf-based exact-GELU: A&S 7.1.26, |erf err| <= 1.5e-7 (<< bf16 ulp)
__device__ __forceinline__ float gelu_f(float v) {
    float u = v * 0.70710678118654752f;
    float x = fabsf(u);
    float t = __builtin_amdgcn_rcpf(fmaf(0.3275911f, x, 1.0f));
    float e = __expf(-u * u);
    float p = fmaf(1.061405429f, t, -1.453152027f);
    p = fmaf(p, t, 1.421413741f);
    p = fmaf(p, t, -0.284496736f);
    p = fmaf(p, t, 0.254829592f);
    float er = 1.0f - p * t * e;
    er = copysignf(er, u);
    return 0.5f * v * (1.0f + er);
}

// ---------------------------------------------------------------------------
// Weight convert + transpose: out[n*K+k] = bf16(in[k*N+n])   (out is [N,K])
// ---------------------------------------------------------------------------
__global__ __launch_bounds__(256) void wtrans(const float* __restrict__ in,
                                              unsigned short* __restrict__ out,
                                              int K, int N) {
    int idx = blockIdx.x * 256 + threadIdx.x;
    if (idx >= K * N) return;
    int n = idx / K, k = idx - n * K;
    out[idx] = f2bf(in[(size_t)k * N + n]);
}

// ---------------------------------------------------------------------------
// LayerNorm -> bf16; WINDOWED=1 adds roll(-3,-3) + window partition.
// ---------------------------------------------------------------------------
template<int WINDOWED>
__global__ __launch_bounds__(256) void ln_kernel(const float* __restrict__ x,
                                                 const float* __restrict__ gamma,
                                                 const float* __restrict__ beta,
                                                 unsigned short* __restrict__ out) {
    int wave = threadIdx.x >> 6;
    int lane = threadIdx.x & 63;
    int tok  = blockIdx.x * 4 + wave;
    int src  = tok;
    if (WINDOWED) {
        int b  = tok / (NWIN * SEQ);
        int r  = tok - b * (NWIN * SEQ);
        int wl = r / SEQ, s = r - wl * SEQ;
        int wy = wl >> 3, wx = wl & 7;
        int i  = s / WINSZ, j = s - i * WINSZ;
        int hp = wy * WINSZ + i + SHIFTSZ; if (hp >= IMG) hp -= IMG;
        int wp = wx * WINSZ + j + SHIFTSZ; if (wp >= IMG) wp -= IMG;
        src = b * (IMG * IMG) + hp * IMG + wp;
    }
    float4 v = *(const float4*)(x + (size_t)src * CDIM + lane * 4);
    float sum = v.x + v.y + v.z + v.w;
    float ss  = v.x*v.x + v.y*v.y + v.z*v.z + v.w*v.w;
#pragma unroll
    for (int off = 32; off; off >>= 1) {
        sum += __shfl_xor(sum, off);
        ss  += __shfl_xor(ss,  off);
    }
    float mu   = sum * (1.0f / CDIM);
    float var  = ss * (1.0f / CDIM) - mu * mu;
    float rstd = rsqrtf(var + EPSLN);
    float4 g  = *(const float4*)(gamma + lane * 4);
    float4 be = *(const float4*)(beta  + lane * 4);
    ushort4 o;
    o.x = f2bf((v.x - mu) * rstd * g.x + be.x);
    o.y = f2bf((v.y - mu) * rstd * g.y + be.y);
    o.z = f2bf((v.z - mu) * rstd * g.z + be.z);
    o.w = f2bf((v.w - mu) * rstd * g.w + be.w);
    *(ushort4*)(out + (size_t)tok * CDIM + lane * 4) = o;
}

// ---------------------------------------------------------------------------
// LDS-FREE bf16 MFMA GEMM: C[M,N] = A[M,K] @ Bt[N,K]^T.
// A and B fragments are 16B-contiguous per lane in row-major [.,K] layout,
// so each wave loads them straight from global (L1/L2 serve the 2x intra-
// block reuse). Register double-buffer = 1 K-step prefetch. ZERO barriers.
// Swapped-operand MFMA: mfma(bf, af) -> lane holds 4 consecutive n at fixed
// m -> packed epilogue stores. Grid: x = column blocks (A reuse in L2/L3).
// ---------------------------------------------------------------------------
#define EPI_QKV  0
#define EPI_PROJ 1
#define EPI_MLP1 2
#define EPI_MLP2 3

template<int EPI>
__global__ __launch_bounds__(256)
void gemm_bt(const unsigned short* __restrict__ A,
             const unsigned short* __restrict__ Bt,
             int K,
             const float* __restrict__ bias,
             const float* __restrict__ resin,
             float* __restrict__ outF,
             unsigned short* __restrict__ outH) {
    int tid  = threadIdx.x;
    int lane = tid & 63, wave = tid >> 6;
    int q4   = lane >> 4, l16 = lane & 15;
    int wm   = wave >> 1, wn = wave & 1;
    int rowBase = blockIdx.y * 128;
    int colBase = blockIdx.x * 128;

    // per-lane fragment base pointers (16B aligned: K % 32 == 0)
    const unsigned short* Ap = A  + (size_t)(rowBase + wm * 64 + l16) * K + q4 * 8;
    const unsigned short* Bp = Bt + (size_t)(colBase + wn * 64 + l16) * K + q4 * 8;
    const size_t aStride = (size_t)16 * K;   // 16 rows between m-fragments

    f32x4 acc[4][4];
#pragma unroll
    for (int i = 0; i < 4; i++)
#pragma unroll
        for (int j = 0; j < 4; j++) acc[i][j] = (f32x4){0.f, 0.f, 0.f, 0.f};

    short8 a0[4], b0[4], a1[4], b1[4];
#pragma unroll
    for (int mi = 0; mi < 4; mi++) a0[mi] = *(const short8*)(Ap + mi * aStride);
#pragma unroll
    for (int ni = 0; ni < 4; ni++) b0[ni] = *(const short8*)(Bp + ni * aStride);

    for (int k0 = 0; k0 < K; k0 += 64) {
        int k1 = k0 + 32;
        int k2 = (k0 + 64 < K) ? k0 + 64 : 0;   // harmless in-bounds dummy on last iter
#pragma unroll
        for (int mi = 0; mi < 4; mi++) a1[mi] = *(const short8*)(Ap + mi * aStride + k1);
#pragma unroll
        for (int ni = 0; ni < 4; ni++) b1[ni] = *(const short8*)(Bp + ni * aStride + k1);
#pragma unroll
        for (int mi = 0; mi < 4; mi++)
#pragma unroll
            for (int ni = 0; ni < 4; ni++)
                acc[mi][ni] = __builtin_amdgcn_mfma_f32_16x16x32_bf16(
                    b0[ni], a0[mi], acc[mi][ni], 0, 0, 0);
#pragma unroll
        for (int mi = 0; mi < 4; mi++) a0[mi] = *(const short8*)(Ap + mi * aStride + k2);
#pragma unroll
        for (int ni = 0; ni < 4; ni++) b0[ni] = *(const short8*)(Bp + ni * aStride + k2);
#pragma unroll
        for (int mi = 0; mi < 4; mi++)
#pragma unroll
            for (int ni = 0; ni < 4; ni++)
                acc[mi][ni] = __builtin_amdgcn_mfma_f32_16x16x32_bf16(
                    b1[ni], a1[mi], acc[mi][ni], 0, 0, 0);
    }

    int mb = rowBase + wm * 64;
    int nb = colBase + wn * 64;
    float4 bias4[4];
#pragma unroll
    for (int ni = 0; ni < 4; ni++)
        bias4[ni] = *(const float4*)(bias + nb + ni * 16 + q4 * 4);

    if (EPI == EPI_QKV) {
        int three = colBase >> 8;   // uniform per block: 0=q, 1=k, 2=v
#pragma unroll
        for (int mi = 0; mi < 4; mi++) {
            int m = mb + mi * 16 + l16;
            int w = m / SEQ, s = m - w * SEQ;
#pragma unroll
            for (int ni = 0; ni < 4; ni++) {
                int n0 = nb + ni * 16 + q4 * 4;
                int hh = (n0 >> 5) & 7, dd0 = n0 & 31;
                const float* bp = (const float*)&bias4[ni];
                if (three == 2) {
#pragma unroll
                    for (int r = 0; r < 4; r++)
                        outH[2 * SZT + (((size_t)(w * NH + hh)) * DH + dd0 + r) * 64 + s] =
                            f2bf(acc[mi][ni][r] + bp[r]);
                } else {
                    float sc = (three == 0) ? QSCALE : 1.0f;
                    ushort4 o;
                    o.x = f2bf((acc[mi][ni][0] + bp[0]) * sc);
                    o.y = f2bf((acc[mi][ni][1] + bp[1]) * sc);
                    o.z = f2bf((acc[mi][ni][2] + bp[2]) * sc);
                    o.w = f2bf((acc[mi][ni][3] + bp[3]) * sc);
                    *(ushort4*)(outH + (size_t)three * SZT +
                                (((size_t)(w * NH + hh)) * SEQ + s) * DH + dd0) = o;
                }
            }
        }
    } else if (EPI == EPI_PROJ) {
#pragma unroll
        for (int mi = 0; mi < 4; mi++) {
            int m = mb + mi * 16 + l16;
            int w = m / SEQ, s = m - w * SEQ;
            int b = w >> 6, wl = w & 63;
            int wy = wl >> 3, wx = wl & 7;
            int ii = s / WINSZ, jj = s - ii * WINSZ;
            int hp = wy * WINSZ + ii + SHIFTSZ; if (hp >= IMG) hp -= IMG;
            int wp = wx * WINSZ + jj + SHIFTSZ; if (wp >= IMG) wp -= IMG;
            size_t tok = (size_t)b * (IMG * IMG) + hp * IMG + wp;
#pragma unroll
            for (int ni = 0; ni < 4; ni++) {
                int n0 = nb + ni * 16 + q4 * 4;
                float4 res = *(const float4*)(resin + tok * CDIM + n0);
                float4 o;
                o.x = acc[mi][ni][0] + bias4[ni].x + res.x;
                o.y = acc[mi][ni][1] + bias4[ni].y + res.y;
                o.z = acc[mi][ni][2] + bias4[ni].z + res.z;
                o.w = acc[mi][ni][3] + bias4[ni].w + res.w;
                *(float4*)(outF + tok * CDIM + n0) = o;
            }
        }
    } else if (EPI == EPI_MLP1) {
#pragma unroll
        for (int mi = 0; mi < 4; mi++) {
            int m = mb + mi * 16 + l16;
#pragma unroll
            for (int ni = 0; ni < 4; ni++) {
                int n0 = nb + ni * 16 + q4 * 4;
                ushort4 o;
                o.x = f2bf(gelu_f(acc[mi][ni][0] + bias4[ni].x));
                o.y = f2bf(gelu_f(acc[mi][ni][1] + bias4[ni].y));
                o.z = f2bf(gelu_f(acc[mi][ni][2] + bias4[ni].z));
                o.w = f2bf(gelu_f(acc[mi][ni][3] + bias4[ni].w));
                *(ushort4*)(outH + (size_t)m * NMLP + n0) = o;
            }
        }
    } else {  // EPI_MLP2
#pragma unroll
        for (int mi = 0; mi < 4; mi++) {
            int m = mb + mi * 16 + l16;
#pragma unroll
            for (int ni = 0; ni < 4; ni++) {
                int n0 = nb + ni * 16 + q4 * 4;
                float4 res = *(const float4*)(resin + (size_t)m * CDIM + n0);
                float4 o;
                o.x = acc[mi][ni][0] + bias4[ni].x + res.x;
                o.y = acc[mi][ni][1] + bias4[ni].y + res.y;
                o.z = acc[mi][ni][2] + bias4[ni].z + res.z;
                o.w = acc[mi][ni][3] + bias4[ni].w + res.w;
                *(float4*)(outF + (size_t)m * CDIM + n0) = o;
            }
        }
    }
}

// ---------------------------------------------------------------------------
// MFMA attention: one WAVE per (window, head). Unchanged (passing).
// ---------------------------------------------------------------------------
__global__ __launch_bounds__(256) void attn_mfma(const unsigned short* __restrict__ qb,
                                                 const unsigned short* __restrict__ kb,
                                                 const unsigned short* __restrict__ vT,
                                                 const float* __restrict__ rel_tab,
                                                 unsigned short* __restrict__ outp) {
    __shared__ __align__(16) unsigned short Pl[4][64 * 64];
    __shared__ float tab[4][169];
    int tid  = threadIdx.x;
    int wave = tid >> 6, lane = tid & 63;
    int q4   = lane >> 4, l16 = lane & 15;
    int job  = blockIdx.x * 4 + wave;
    int w    = job >> 3, h = job & 7;

    for (int i = lane; i < 169; i += 64) tab[wave][i] = rel_tab[i * NH + h];

    const unsigned short* qg = qb + (size_t)(w * NH + h) * SEQ * DH;
    const unsigned short* kg = kb + (size_t)(w * NH + h) * SEQ * DH;
    short8 aq[4], bk[4];
#pragma unroll
    for (int mi = 0; mi < 4; mi++)
        aq[mi] = *(const short8*)(qg + (mi * 16 + l16) * DH + q4 * 8);
#pragma unroll
    for (int ni = 0; ni < 4; ni++)
        bk[ni] = *(const short8*)(kg + (ni * 16 + l16) * DH + q4 * 8);

    f32x4 acc[4][4];
#pragma unroll
    for (int i = 0; i < 4; i++)
#pragma unroll
        for (int j = 0; j < 4; j++) acc[i][j] = (f32x4){0.f, 0.f, 0.f, 0.f};
#pragma unroll
    for (int mi = 0; mi < 4; mi++)
#pragma unroll
        for (int ni = 0; ni < 4; ni++)
            acc[mi][ni] = __builtin_amdgcn_mfma_f32_16x16x32_bf16(
                aq[mi], bk[ni], acc[mi][ni], 0, 0, 0);

    int wl = w & 63;
    int wy = wl >> 3, wx = wl & 7;
    bool edge = (wy == 7) || (wx == 7);

    int itv[4], jtv[4], ltv[4];
#pragma unroll
    for (int ni = 0; ni < 4; ni++) {
        int t  = ni * 16 + l16;
        int it = (t * 37) >> 8;
        int jt = t - it * 7;
        itv[ni] = it; jtv[ni] = jt;
        int lab;
        if (wx == 7 && jt < 4) lab = 0;
        else {
            int lh = (wy == 7) ? ((it < 4) ? 1 : 2) : 0;
            lab = lh * 3 + ((wx == 7) ? 2 : 0);
        }
        ltv[ni] = lab;
    }

    float rinv[4][4];
#pragma unroll
    for (int mi = 0; mi < 4; mi++) {
#pragma unroll
        for (int r = 0; r < 4; r++) {
            int s  = mi * 16 + q4 * 4 + r;
            int is = (s * 37) >> 8;
            int js = s - is * 7;
            int lab_s;
            if (wx == 7 && js < 4) lab_s = 0;
            else {
                int lh = (wy == 7) ? ((is < 4) ? 1 : 2) : 0;
                lab_s = lh * 3 + ((wx == 7) ? 2 : 0);
            }
            float vv[4];
#pragma unroll
            for (int ni = 0; ni < 4; ni++) {
                int t = ni * 16 + l16;
                float a = acc[mi][ni][r];
                if (t < SEQ) {
                    int idx = (is - itv[ni] + 6) * 13 + (js - jtv[ni] + 6);
                    idx = idx < 0 ? 0 : (idx > 168 ? 168 : idx);
                    a += tab[wave][idx];
                    if (edge && lab_s != ltv[ni]) a -= 100.0f;
                } else {
                    a = -1e30f;
                }
                vv[ni] = a;
            }
            float mx = fmaxf(fmaxf(vv[0], vv[1]), fmaxf(vv[2], vv[3]));
#pragma unroll
            for (int off = 1; off < 16; off <<= 1) mx = fmaxf(mx, __shfl_xor(mx, off));
            float sm = 0.0f;
            unsigned short pb[4];
#pragma unroll
            for (int ni = 0; ni < 4; ni++) {
                float p = __expf(vv[ni] - mx);
                sm += p;
                pb[ni] = f2bf(p);
            }
#pragma unroll
            for (int off = 1; off < 16; off <<= 1) sm += __shfl_xor(sm, off);
            rinv[mi][r] = 1.0f / sm;
#pragma unroll
            for (int ni = 0; ni < 4; ni++) {
                int t  = ni * 16 + l16;
                int kbk = t >> 3, j = t & 7;
                Pl[wave][s * 64 + ((kbk ^ (s & 7)) * 8) + j] = pb[ni];
            }
        }
    }
    __syncthreads();

    short8 pa[4][2];
#pragma unroll
    for (int mi = 0; mi < 4; mi++)
#pragma unroll
        for (int ks = 0; ks < 2; ks++) {
            int m  = mi * 16 + l16;
            int kbk = ks * 4 + q4;
            pa[mi][ks] = *(const short8*)&Pl[wave][m * 64 + ((kbk ^ (m & 7)) * 8)];
        }
    const unsigned short* vg = vT + (size_t)(w * NH + h) * DH * 64;
    short8 bv[2][2];
#pragma unroll
    for (int n2 = 0; n2 < 2; n2++)
#pragma unroll
        for (int ks = 0; ks < 2; ks++)
            bv[n2][ks] = *(const short8*)(vg + (n2 * 16 + l16) * 64 + ks * 32 + q4 * 8);

    f32x4 o[4][2];
#pragma unroll
    for (int mi = 0; mi < 4; mi++)
#pragma unroll
        for (int n2 = 0; n2 < 2; n2++) o[mi][n2] = (f32x4){0.f, 0.f, 0.f, 0.f};
#pragma unroll
    for (int ks = 0; ks < 2; ks++)
#pragma unroll
        for (int mi = 0; mi < 4; mi++)
#pragma unroll
            for (int n2 = 0; n2 < 2; n2++)
                o[mi][n2] = __builtin_amdgcn_mfma_f32_16x16x32_bf16(
                    pa[mi][ks], bv[n2][ks], o[mi][n2], 0, 0, 0);

#pragma unroll
    for (int mi = 0; mi < 4; mi++)
#pragma unroll
        for (int r = 0; r < 4; r++) {
            int s = mi * 16 + q4 * 4 + r;
            if (s < SEQ) {
#pragma unroll
                for (int n2 = 0; n2 < 2; n2++) {
                    int d = n2 * 16 + l16;
                    outp[((size_t)w * SEQ + s) * CDIM + h * DH + d] =
                        f2bf(o[mi][n2][r] * rinv[mi][r]);
                }
            }
        }
}

// ---------------------------------------------------------------------------
extern "C" void kernel_launch(void* const* d_in, const int* in_sizes, int n_in,
                              void* d_out, int out_size, void* d_ws, size_t ws_size,
                              hipStream_t stream) {
    const float* x      = (const float*)d_in[0];
    const float* gamma  = (const float*)d_in[1];
    const float* beta   = (const float*)d_in[2];
    const float* qkv_w  = (const float*)d_in[3];
    const float* qkv_b  = (const float*)d_in[4];
    const float* proj_w = (const float*)d_in[5];
    const float* proj_b = (const float*)d_in[6];
    const float* rel_t  = (const float*)d_in[7];
    const float* mlp_w1 = (const float*)d_in[8];
    const float* mlp_b1 = (const float*)d_in[9];
    const float* mlp_w2 = (const float*)d_in[10];
    const float* mlp_b2 = (const float*)d_in[11];
    float* outp = (float*)d_out;

    const size_t VTSZ = (size_t)BNW * NH * DH * 64;   // 33,554,432
    unsigned short* xw_bf   = (unsigned short*)d_ws;              // SZT
    unsigned short* qkv_bf  = xw_bf + SZT;                        // q:SZT, k:SZT, vT:VTSZ
    unsigned short* attn_bf = qkv_bf + 2 * SZT + VTSZ;            // SZT
    float*          y1      = (float*)(attn_bf + SZT);            // SZT floats
    unsigned short* wt_bf   = (unsigned short*)(y1 + SZT);        // 786432
    unsigned short* h_bf    = qkv_bf;   // reuse q+k+vT+attn (>= NTOK*NMLP)

    unsigned short* qkvW  = wt_bf;
    unsigned short* projW = qkvW  + 768 * 256;
    unsigned short* mlp1W = projW + 256 * 256;
    unsigned short* mlp2W = mlp1W + 1024 * 256;

    wtrans<<<(768 * 256 + 255) / 256, 256, 0, stream>>>(qkv_w, qkvW, CDIM, 3 * CDIM);
    wtrans<<<(256 * 256 + 255) / 256, 256, 0, stream>>>(proj_w, projW, CDIM, CDIM);
    wtrans<<<(1024 * 256 + 255) / 256, 256, 0, stream>>>(mlp_w1, mlp1W, CDIM, NMLP);
    wtrans<<<(256 * 1024 + 255) / 256, 256, 0, stream>>>(mlp_w2, mlp2W, NMLP, CDIM);

    ln_kernel<1><<<NTOK / 4, 256, 0, stream>>>(x, gamma, beta, xw_bf);
    gemm_bt<EPI_QKV><<<dim3(6, NTOK / 128), 256, 0, stream>>>(
        xw_bf, qkvW, CDIM, qkv_b, nullptr, nullptr, qkv_bf);
    attn_mfma<<<BNW * NH / 4, 256, 0, stream>>>(
        qkv_bf, qkv_bf + SZT, qkv_bf + 2 * SZT, rel_t, attn_bf);
    gemm_bt<EPI_PROJ><<<dim3(2, NTOK / 128), 256, 0, stream>>>(
        attn_bf, projW, CDIM, proj_b, x, y1, nullptr);
    ln_kernel<0><<<NTOK / 4, 256, 0, stream>>>(y1, gamma, beta, xw_bf);
    gemm_bt<EPI_MLP1><<<dim3(8, NTOK / 128), 256, 0, stream>>>(
        xw_bf, mlp1W, CDIM, mlp_b1, nullptr, nullptr, h_bf);
    gemm_bt<EPI_MLP2><<<dim3(2, NTOK / 128), 256, 0, stream>>>(
        h_bf, mlp2W, NMLP, mlp_b2, y1, outp, nullptr);
}